// Round 3
// baseline (10014.371 us; speedup 1.0000x reference)
//
#include <hip/hip_runtime.h>
#include <hip/hip_bf16.h>

#define H 1024
#define BATCH 128
#define INF 171
#define KXP 192
#define T_TOT 100
#define T_COND 50
#define NDEC 192
#define OUTF 171

typedef __bf16 bf16_t;
typedef __attribute__((ext_vector_type(8))) __bf16 bf16x8;
typedef __attribute__((ext_vector_type(4))) float f32x4;

__device__ __forceinline__ float sigm(float x) { return 1.0f / (1.0f + expf(-x)); }

// ---------------- prep kernels (run every call; idempotent) ----------------

// Split fp32 weights into bf16 hi/lo, optionally interleaving gate rows
// (out row r' = 4*j + g  <-  src row g*H + j), zero-padding K to Kout.
__global__ void prep_weights(const float* __restrict__ W, bf16_t* __restrict__ hi,
                             bf16_t* __restrict__ lo, int rows_out, int rows_valid,
                             int Kin, int Kout, int interleave)
{
    int total = rows_out * Kout;
    for (int idx = blockIdx.x * blockDim.x + threadIdx.x; idx < total;
         idx += gridDim.x * blockDim.x) {
        int r = idx / Kout;
        int k = idx - r * Kout;
        int src = interleave ? ((r & 3) * H + (r >> 2)) : r;
        float v = 0.0f;
        if (k < Kin && src < rows_valid) v = W[(size_t)src * Kin + k];
        bf16_t h = (bf16_t)v;
        hi[idx] = h;
        lo[idx] = (bf16_t)(v - (float)h);
    }
}

__global__ void prep_bias(const float* __restrict__ bi1, const float* __restrict__ bh1,
                          const float* __restrict__ bi2, const float* __restrict__ bh2,
                          const float* __restrict__ bi3, const float* __restrict__ bh3,
                          const float* __restrict__ bd_in, float* __restrict__ bias3,
                          float* __restrict__ bd_out)
{
    int i = blockIdx.x * blockDim.x + threadIdx.x;
    if (i < 3 * 4096) {
        int L = i >> 12, r = i & 4095;
        int src = (r & 3) * H + (r >> 2);   // interleaved -> source row
        const float* a = (L == 0) ? bi1 : (L == 1) ? bi2 : bi3;
        const float* b = (L == 0) ? bh1 : (L == 1) ? bh2 : bh3;
        bias3[i] = a[src] + b[src];
    } else if (i < 3 * 4096 + NDEC) {
        int n = i - 3 * 4096;
        bd_out[n] = (n < OUTF) ? bd_in[n] : 0.0f;
    }
}

// initial_seq [B][50][INF] -> xseq splits [50][B][KXP] (zero-padded)
__global__ void prep_seq(const float* __restrict__ seq, bf16_t* __restrict__ hi,
                         bf16_t* __restrict__ lo)
{
    int total = T_COND * BATCH * KXP;
    for (int idx = blockIdx.x * blockDim.x + threadIdx.x; idx < total;
         idx += gridDim.x * blockDim.x) {
        int t = idx / (BATCH * KXP);
        int rem = idx - t * (BATCH * KXP);
        int b = rem / KXP;
        int k = rem - b * KXP;
        float v = (k < INF) ? seq[((size_t)b * T_COND + t) * INF + k] : 0.0f;
        bf16_t h = (bf16_t)v;
        hi[idx] = h;
        lo[idx] = (bf16_t)(v - (float)h);
    }
}

// ---------------- fused LSTM layer: gates GEMM (3-product bf16 split MFMA)
//                  + cell update epilogue ----------------
// grid: (64 n-blocks of 64 interleaved gate cols, 4 m-blocks of 32 batch rows)
// block: 128 threads = 2 waves, wave-tile 32x32, BK=64.
__global__ __launch_bounds__(128)
void lstm_layer(const bf16_t* __restrict__ xhi, const bf16_t* __restrict__ xlo, int ldx,
                const bf16_t* __restrict__ wxhi, const bf16_t* __restrict__ wxlo,
                const bf16_t* __restrict__ hhi, const bf16_t* __restrict__ hlo,
                const bf16_t* __restrict__ whhi, const bf16_t* __restrict__ whlo,
                const float* __restrict__ bias,   // [4096] interleaved (layer slice)
                float* __restrict__ cst,          // [128][1024] fp32 in/out
                bf16_t* __restrict__ ohi, bf16_t* __restrict__ olo)  // h splits out
{
    __shared__ __align__(16) unsigned char smem[192 * 72 * 2];   // 27648 B
    bf16_t* sAh = (bf16_t*)smem;        // [32][72]
    bf16_t* sAl = sAh + 32 * 72;
    bf16_t* sBh = sAl + 32 * 72;        // [64][72]
    bf16_t* sBl = sBh + 64 * 72;

    const int tid = threadIdx.x;
    const int lane = tid & 63;
    const int wv = tid >> 6;             // 0..1 (n-half of the 64-col tile)
    const int m0 = blockIdx.y * 32;
    const int n0 = blockIdx.x * 64;

    f32x4 acc[2][2];
#pragma unroll
    for (int i = 0; i < 2; ++i)
#pragma unroll
        for (int j = 0; j < 2; ++j) acc[i][j] = (f32x4){0.f, 0.f, 0.f, 0.f};

    const int c8 = (tid & 7) * 8;
    const int r0 = tid >> 3;             // 0..15
    const int lr = lane & 15;
    const int lk = (lane >> 4) * 8;

#pragma unroll 1
    for (int seg = 0; seg < 2; ++seg) {
        const bf16_t* Ah = seg ? hhi : xhi;
        const bf16_t* Al = seg ? hlo : xlo;
        const bf16_t* Bh = seg ? whhi : wxhi;
        const bf16_t* Bl = seg ? whlo : wxlo;
        const int K = seg ? H : ldx;
#pragma unroll 1
        for (int k0 = 0; k0 < K; k0 += 64) {
            __syncthreads();
            // stage A (x or h): 32 rows x 64 k, hi+lo
#pragma unroll
            for (int rr = 0; rr < 2; ++rr) {
                int r = r0 + rr * 16;
                size_t g = (size_t)(m0 + r) * K + k0 + c8;
                *(uint4*)&sAh[r * 72 + c8] = *(const uint4*)&Ah[g];
                *(uint4*)&sAl[r * 72 + c8] = *(const uint4*)&Al[g];
            }
            // stage B (W'): 64 rows x 64 k, hi+lo
#pragma unroll
            for (int rr = 0; rr < 4; ++rr) {
                int r = r0 + rr * 16;
                size_t g = (size_t)(n0 + r) * K + k0 + c8;
                *(uint4*)&sBh[r * 72 + c8] = *(const uint4*)&Bh[g];
                *(uint4*)&sBl[r * 72 + c8] = *(const uint4*)&Bl[g];
            }
            __syncthreads();
#pragma unroll
            for (int kk = 0; kk < 64; kk += 32) {
                bf16x8 ah[2], al[2], bh[2], bl[2];
#pragma unroll
                for (int mt = 0; mt < 2; ++mt) {
                    ah[mt] = *(const bf16x8*)&sAh[(mt * 16 + lr) * 72 + kk + lk];
                    al[mt] = *(const bf16x8*)&sAl[(mt * 16 + lr) * 72 + kk + lk];
                }
#pragma unroll
                for (int nt = 0; nt < 2; ++nt) {
                    bh[nt] = *(const bf16x8*)&sBh[(wv * 32 + nt * 16 + lr) * 72 + kk + lk];
                    bl[nt] = *(const bf16x8*)&sBl[(wv * 32 + nt * 16 + lr) * 72 + kk + lk];
                }
#pragma unroll
                for (int mt = 0; mt < 2; ++mt)
#pragma unroll
                    for (int nt = 0; nt < 2; ++nt) {
                        acc[mt][nt] = __builtin_amdgcn_mfma_f32_16x16x32_bf16(ah[mt], bh[nt], acc[mt][nt], 0, 0, 0);
                        acc[mt][nt] = __builtin_amdgcn_mfma_f32_16x16x32_bf16(ah[mt], bl[nt], acc[mt][nt], 0, 0, 0);
                        acc[mt][nt] = __builtin_amdgcn_mfma_f32_16x16x32_bf16(al[mt], bh[nt], acc[mt][nt], 0, 0, 0);
                    }
            }
        }
    }

    // ---- epilogue: gates -> LDS, then fused cell update ----
    __syncthreads();
    float* G = (float*)smem;             // [32][68] fp32, reuses tile LDS
#pragma unroll
    for (int mt = 0; mt < 2; ++mt)
#pragma unroll
        for (int nt = 0; nt < 2; ++nt)
#pragma unroll
            for (int q = 0; q < 4; ++q)
                G[(mt * 16 + (lane >> 4) * 4 + q) * 68 + wv * 32 + nt * 16 + lr] = acc[mt][nt][q];
    __syncthreads();

    {
        const int j = tid & 15;          // j within block (16 j's)
        const int rb = tid >> 4;         // 0..7
        const int jg = (n0 >> 2) + j;    // global j in [0,1024)
        const float4 bb = *(const float4*)&bias[n0 + j * 4];
#pragma unroll
        for (int rr = 0; rr < 4; ++rr) {
            int r = rb + rr * 8;
            int b = m0 + r;
            const float* gr = &G[r * 68 + j * 4];
            float iv = sigm(gr[0] + bb.x);
            float fv = sigm(gr[1] + bb.y);
            float gv = tanhf(gr[2] + bb.z);
            float ov = sigm(gr[3] + bb.w);
            size_t ci = (size_t)b * H + jg;
            float cn = fv * cst[ci] + iv * gv;
            cst[ci] = cn;
            float hn = ov * tanhf(cn);
            bf16_t hh = (bf16_t)hn;
            ohi[ci] = hh;
            olo[ci] = (bf16_t)(hn - (float)hh);
        }
    }
}

// ---------------- decoder GEMM (MFMA, 3-product) + output + feedback split ----
// grid: (6 n-blocks of 32, 4 m-blocks of 32), block: 64 threads (1 wave)
__global__ __launch_bounds__(64)
void dec_kernel(const bf16_t* __restrict__ hhi, const bf16_t* __restrict__ hlo,
                const bf16_t* __restrict__ whi, const bf16_t* __restrict__ wlo,
                const float* __restrict__ bd, float* __restrict__ out, int t,
                bf16_t* __restrict__ xfhi, bf16_t* __restrict__ xflo)
{
    __shared__ __align__(16) bf16_t sm[4 * 32 * 72];
    bf16_t* sAh = sm;
    bf16_t* sAl = sAh + 32 * 72;
    bf16_t* sBh = sAl + 32 * 72;
    bf16_t* sBl = sBh + 32 * 72;

    const int tid = threadIdx.x;         // == lane
    const int m0 = blockIdx.y * 32;
    const int n0 = blockIdx.x * 32;

    f32x4 acc[2][2];
#pragma unroll
    for (int i = 0; i < 2; ++i)
#pragma unroll
        for (int j = 0; j < 2; ++j) acc[i][j] = (f32x4){0.f, 0.f, 0.f, 0.f};

    const int c8 = (tid & 7) * 8;
    const int r0 = tid >> 3;             // 0..7
    const int lr = tid & 15;
    const int lk = (tid >> 4) * 8;

#pragma unroll 1
    for (int k0 = 0; k0 < H; k0 += 64) {
        __syncthreads();
#pragma unroll
        for (int rr = 0; rr < 4; ++rr) {
            int r = r0 + rr * 8;
            size_t ga = (size_t)(m0 + r) * H + k0 + c8;
            *(uint4*)&sAh[r * 72 + c8] = *(const uint4*)&hhi[ga];
            *(uint4*)&sAl[r * 72 + c8] = *(const uint4*)&hlo[ga];
            size_t gb = (size_t)(n0 + r) * H + k0 + c8;
            *(uint4*)&sBh[r * 72 + c8] = *(const uint4*)&whi[gb];
            *(uint4*)&sBl[r * 72 + c8] = *(const uint4*)&wlo[gb];
        }
        __syncthreads();
#pragma unroll
        for (int kk = 0; kk < 64; kk += 32) {
            bf16x8 ah[2], al[2], bh[2], bl[2];
#pragma unroll
            for (int mt = 0; mt < 2; ++mt) {
                ah[mt] = *(const bf16x8*)&sAh[(mt * 16 + lr) * 72 + kk + lk];
                al[mt] = *(const bf16x8*)&sAl[(mt * 16 + lr) * 72 + kk + lk];
            }
#pragma unroll
            for (int nt = 0; nt < 2; ++nt) {
                bh[nt] = *(const bf16x8*)&sBh[(nt * 16 + lr) * 72 + kk + lk];
                bl[nt] = *(const bf16x8*)&sBl[(nt * 16 + lr) * 72 + kk + lk];
            }
#pragma unroll
            for (int mt = 0; mt < 2; ++mt)
#pragma unroll
                for (int nt = 0; nt < 2; ++nt) {
                    acc[mt][nt] = __builtin_amdgcn_mfma_f32_16x16x32_bf16(ah[mt], bh[nt], acc[mt][nt], 0, 0, 0);
                    acc[mt][nt] = __builtin_amdgcn_mfma_f32_16x16x32_bf16(ah[mt], bl[nt], acc[mt][nt], 0, 0, 0);
                    acc[mt][nt] = __builtin_amdgcn_mfma_f32_16x16x32_bf16(al[mt], bh[nt], acc[mt][nt], 0, 0, 0);
                }
        }
    }
#pragma unroll
    for (int mt = 0; mt < 2; ++mt)
#pragma unroll
        for (int nt = 0; nt < 2; ++nt)
#pragma unroll
            for (int q = 0; q < 4; ++q) {
                int brow = m0 + mt * 16 + (tid >> 4) * 4 + q;
                int n = n0 + nt * 16 + lr;
                float v = acc[mt][nt][q] + bd[n];
                float vf = (n < OUTF) ? v : 0.0f;
                if (n < OUTF) out[((size_t)brow * T_TOT + t) * OUTF + n] = v;
                bf16_t hh = (bf16_t)vf;
                xfhi[(size_t)brow * KXP + n] = hh;
                xflo[(size_t)brow * KXP + n] = (bf16_t)(vf - (float)hh);
            }
}

// ---------------- host launch ----------------
extern "C" void kernel_launch(void* const* d_in, const int* in_sizes, int n_in,
                              void* d_out, int out_size, void* d_ws, size_t ws_size,
                              hipStream_t stream)
{
    (void)in_sizes; (void)n_in; (void)out_size;
    const float* seq   = (const float*)d_in[0];
    const float* Wih1  = (const float*)d_in[1];
    const float* Whh1  = (const float*)d_in[2];
    const float* bih1  = (const float*)d_in[3];
    const float* bhh1  = (const float*)d_in[4];
    const float* Wih2  = (const float*)d_in[5];
    const float* Whh2  = (const float*)d_in[6];
    const float* bih2  = (const float*)d_in[7];
    const float* bhh2  = (const float*)d_in[8];
    const float* Wih3  = (const float*)d_in[9];
    const float* Whh3  = (const float*)d_in[10];
    const float* bih3  = (const float*)d_in[11];
    const float* bhh3  = (const float*)d_in[12];
    const float* Wdec  = (const float*)d_in[13];
    const float* bdecI = (const float*)d_in[14];
    float* out = (float*)d_out;

    size_t off = 0;
    auto alloc = [&](size_t bytes) -> void* {
        void* p = (char*)d_ws + off;
        off += (bytes + 255) & ~(size_t)255;
        return p;
    };

    // ---- zero region (one contiguous memset): c[3], h splits buf0 ----
    float* c0 = (float*)alloc((size_t)BATCH * H * 4);
    float* c1 = (float*)alloc((size_t)BATCH * H * 4);
    float* c2 = (float*)alloc((size_t)BATCH * H * 4);
    bf16_t *hh_[3][2], *hl_[3][2];
    for (int L = 0; L < 3; ++L) {
        hh_[L][0] = (bf16_t*)alloc((size_t)BATCH * H * 2);
        hl_[L][0] = (bf16_t*)alloc((size_t)BATCH * H * 2);
    }
    size_t zero_bytes = off;
    for (int L = 0; L < 3; ++L) {
        hh_[L][1] = (bf16_t*)alloc((size_t)BATCH * H * 2);
        hl_[L][1] = (bf16_t*)alloc((size_t)BATCH * H * 2);
    }
    float* bias3 = (float*)alloc(3 * 4096 * 4);
    float* bd    = (float*)alloc(NDEC * 4);

    bf16_t* w1xh = (bf16_t*)alloc((size_t)4096 * KXP * 2);
    bf16_t* w1xl = (bf16_t*)alloc((size_t)4096 * KXP * 2);
    bf16_t* w1hh = (bf16_t*)alloc((size_t)4096 * H * 2);
    bf16_t* w1hl = (bf16_t*)alloc((size_t)4096 * H * 2);
    bf16_t* w2xh = (bf16_t*)alloc((size_t)4096 * H * 2);
    bf16_t* w2xl = (bf16_t*)alloc((size_t)4096 * H * 2);
    bf16_t* w2hh = (bf16_t*)alloc((size_t)4096 * H * 2);
    bf16_t* w2hl = (bf16_t*)alloc((size_t)4096 * H * 2);
    bf16_t* w3xh = (bf16_t*)alloc((size_t)4096 * H * 2);
    bf16_t* w3xl = (bf16_t*)alloc((size_t)4096 * H * 2);
    bf16_t* w3hh = (bf16_t*)alloc((size_t)4096 * H * 2);
    bf16_t* w3hl = (bf16_t*)alloc((size_t)4096 * H * 2);
    bf16_t* wdh  = (bf16_t*)alloc((size_t)NDEC * H * 2);
    bf16_t* wdl  = (bf16_t*)alloc((size_t)NDEC * H * 2);
    bf16_t* xsh  = (bf16_t*)alloc((size_t)T_COND * BATCH * KXP * 2);
    bf16_t* xsl  = (bf16_t*)alloc((size_t)T_COND * BATCH * KXP * 2);
    bf16_t* xfh  = (bf16_t*)alloc((size_t)BATCH * KXP * 2);
    bf16_t* xfl  = (bf16_t*)alloc((size_t)BATCH * KXP * 2);

    if (ws_size < off) return;  // insufficient scratch -> visible as absmax fail

    hipMemsetAsync(c0, 0, zero_bytes, stream);

    // ---- weight / bias / sequence prep (every call) ----
    prep_weights<<<dim3(2048), 256, 0, stream>>>(Wih1, w1xh, w1xl, 4096, 4096, INF, KXP, 1);
    prep_weights<<<dim3(8192), 256, 0, stream>>>(Whh1, w1hh, w1hl, 4096, 4096, H, H, 1);
    prep_weights<<<dim3(8192), 256, 0, stream>>>(Wih2, w2xh, w2xl, 4096, 4096, H, H, 1);
    prep_weights<<<dim3(8192), 256, 0, stream>>>(Whh2, w2hh, w2hl, 4096, 4096, H, H, 1);
    prep_weights<<<dim3(8192), 256, 0, stream>>>(Wih3, w3xh, w3xl, 4096, 4096, H, H, 1);
    prep_weights<<<dim3(8192), 256, 0, stream>>>(Whh3, w3hh, w3hl, 4096, 4096, H, H, 1);
    prep_weights<<<dim3(1024), 256, 0, stream>>>(Wdec, wdh, wdl, NDEC, OUTF, H, H, 0);
    prep_bias<<<dim3(49), 256, 0, stream>>>(bih1, bhh1, bih2, bhh2, bih3, bhh3, bdecI, bias3, bd);
    prep_seq<<<dim3(2048), 256, 0, stream>>>(seq, xsh, xsl);

    // ---- 100 sequential steps ----
    for (int t = 0; t < T_TOT; ++t) {
        const bf16_t *xh, *xl;
        if (t < T_COND) {
            xh = xsh + (size_t)t * BATCH * KXP;
            xl = xsl + (size_t)t * BATCH * KXP;
        } else {
            xh = xfh;
            xl = xfl;
        }
        int pr = t & 1, pw = pr ^ 1;
        lstm_layer<<<dim3(64, 4), 128, 0, stream>>>(
            xh, xl, KXP, w1xh, w1xl,
            hh_[0][pr], hl_[0][pr], w1hh, w1hl,
            bias3, c0, hh_[0][pw], hl_[0][pw]);
        lstm_layer<<<dim3(64, 4), 128, 0, stream>>>(
            hh_[0][pw], hl_[0][pw], H, w2xh, w2xl,
            hh_[1][pr], hl_[1][pr], w2hh, w2hl,
            bias3 + 4096, c1, hh_[1][pw], hl_[1][pw]);
        lstm_layer<<<dim3(64, 4), 128, 0, stream>>>(
            hh_[1][pw], hl_[1][pw], H, w3xh, w3xl,
            hh_[2][pr], hl_[2][pr], w3hh, w3hl,
            bias3 + 8192, c2, hh_[2][pw], hl_[2][pw]);
        dec_kernel<<<dim3(6, 4), 64, 0, stream>>>(
            hh_[2][pw], hl_[2][pw], wdh, wdl, bd, out, t, xfh, xfl);
    }
}